// Round 8
// baseline (3209.249 us; speedup 1.0000x reference)
//
#include <hip/hip_runtime.h>
#include <cmath>

// Batched log(SPD 64x64), one-sided Jacobi, LDS-resident columns.
// One 64-thread block per matrix; lane k owns column k in VGPRs, mirrored in
// LDS. r8: ALL LDS mirror traffic via inline-asm ds_read_b128/ds_write_b128
// (opaque to compiler) -> compiler cannot re-read LDS instead of keeping the
// columns in registers (r2-r7 had VGPR=76-88: both columns were LDS-resident,
// ~2x the minimum DS traffic per round; DS pipe was saturated).
// Convergence: MAXSWEEP 16 + mid-sweep quiet exit (r7 proved fixed-9 fails).

#define MAXSWEEP 16
#define JTOL 5e-4f
#define XTOL 2e-3f
#define TSTRIDE 68  // floats = 17 float4s (odd) -> conflict-free b128 pattern

typedef float f32x4 __attribute__((ext_vector_type(4)));

#define DS_READ(dst, addr, OFF) \
    asm volatile("ds_read_b128 %0, %1 offset:" OFF : "=v"(dst) : "v"(addr))
#define DS_WRITE(addr, src, OFF) \
    asm volatile("ds_write_b128 %0, %1 offset:" OFF : : "v"(addr), "v"(src) : "memory")

#define FOR16(OP) OP(0,"0") OP(1,"16") OP(2,"32") OP(3,"48") OP(4,"64") OP(5,"80") \
    OP(6,"96") OP(7,"112") OP(8,"128") OP(9,"144") OP(10,"160") OP(11,"176") \
    OP(12,"192") OP(13,"208") OP(14,"224") OP(15,"240")

__global__ __launch_bounds__(64, 2)
void logeig_kernel(const float* __restrict__ X, float* __restrict__ Out, int B)
{
    const int lane = threadIdx.x & 63;
    const long b = blockIdx.x;

    __shared__ float T[64 * TSTRIDE];   // row k = column k of F; [64..67] pad/w

    const float* Xb = X + b * 4096;
    float*       Ob = Out + b * 4096;

    // 32-bit LDS byte offsets for inline-asm DS ops
    const unsigned tbase = (unsigned)(size_t)(void*)T;
    const unsigned maddr = tbase + (unsigned)(lane * (TSTRIDE * 4));

    // Column `lane` of X == row `lane` (symmetric) -> contiguous load.
    f32x4 fq[16];
    {
        const float4* Xr = reinterpret_cast<const float4*>(Xb + lane * 64);
#pragma unroll
        for (int i = 0; i < 16; ++i) {
            const float4 v = Xr[i];
            fq[i] = f32x4{v.x, v.y, v.z, v.w};
        }
    }
#define WRF(i, o) DS_WRITE(maddr, fq[i], o);
    FOR16(WRF)    // mirror column into LDS (opaque)

    // unscaled squared column norm (tracked incrementally) + true scale rho
    float app;
    {
        f32x4 a0 = 0.f, a1 = 0.f, a2 = 0.f, a3 = 0.f;
#pragma unroll
        for (int i = 0; i < 16; i += 4) {
            a0 = __builtin_elementwise_fma(fq[i+0], fq[i+0], a0);
            a1 = __builtin_elementwise_fma(fq[i+1], fq[i+1], a1);
            a2 = __builtin_elementwise_fma(fq[i+2], fq[i+2], a2);
            a3 = __builtin_elementwise_fma(fq[i+3], fq[i+3], a3);
        }
        const f32x4 s = (a0 + a1) + (a2 + a3);
        app = (s.x + s.y) + (s.z + s.w);
    }
    float rho = 1.0f;
    int quiet = 0;                      // consecutive rounds, all pairs < XTOL

    for (int sweep = 0; sweep < MAXSWEEP; ++sweep) {
        for (int r = 1; r < 64; ++r) {
            // XOR tournament: pair (i,j) meets exactly once per sweep at r=i^j
            const int partner = lane ^ r;
            const unsigned paddr = tbase + (unsigned)(partner * (TSTRIDE * 4));

            const float aqq = __int_as_float(
                __builtin_amdgcn_ds_bpermute(partner << 2, __float_as_int(app)));

            // fetch partner's column: 16 x ds_read_b128 (opaque -> stays in VGPRs)
            f32x4 tq[16];
#define RDT(i, o) DS_READ(tq[i], paddr, o);
            FOR16(RDT)
            asm volatile("s_waitcnt lgkmcnt(0)" ::: "memory");
            __builtin_amdgcn_sched_barrier(0);

            // apq: commutative products, identical order on both lanes of the
            // pair -> bit-identical -> identical decisions & angles.
            float apq;
            {
                f32x4 a0 = 0.f, a1 = 0.f, a2 = 0.f, a3 = 0.f;
#pragma unroll
                for (int i = 0; i < 16; i += 4) {
                    a0 = __builtin_elementwise_fma(fq[i+0], tq[i+0], a0);
                    a1 = __builtin_elementwise_fma(fq[i+1], tq[i+1], a1);
                    a2 = __builtin_elementwise_fma(fq[i+2], tq[i+2], a2);
                    a3 = __builtin_elementwise_fma(fq[i+3], tq[i+3], a3);
                }
                const f32x4 s = (a0 + a1) + (a2 + a3);
                apq = (s.x + s.y) + (s.z + s.w);
            }

            const float rel  = sqrtf(app * aqq);
            const bool  rot  = fabsf(apq) > JTOL * rel;
            const bool  bigr = __any(fabsf(apq) > XTOL * rel);

            if (__any(rot)) {
                const float rhoq = __int_as_float(
                    __builtin_amdgcn_ds_bpermute(partner << 2, __float_as_int(rho)));
                // canonical orientation: p = min-lane, q = max-lane. Pair-shared
                // quantities from commutative products -> bit-identical angles.
                const bool  isp  = lane < partner;
                const float tapp = (rho  * rho ) * app;
                const float taqq = (rhoq * rhoq) * aqq;
                const float prod = (rho * rhoq) * apq;
                const float App = isp ? tapp : taqq;
                const float Aqq = isp ? taqq : tapp;
                const float tau = (Aqq - App) / (2.f * prod);
                const float t0  = copysignf(1.f, tau) / (fabsf(tau) + sqrtf(fmaf(tau, tau, 1.f)));
                const float c0  = rsqrtf(fmaf(t0, t0, 1.f));
                const float tl  = isp ? t0 : -t0;
                const float alpha = rot ? tl * (rhoq * __builtin_amdgcn_rcpf(rho)) : 0.f;

                const f32x4 na = {-alpha, -alpha, -alpha, -alpha};
#pragma unroll
                for (int i = 0; i < 16; ++i)
                    fq[i] = __builtin_elementwise_fma(na, tq[i], fq[i]);
                // exact 2x2 identities (guard non-rotating lanes)
                app = rot ? (app - alpha * apq) * fmaf(t0, t0, 1.f) : app;
                rho = rot ? rho * c0 : rho;

                // overflow guard for deferred scaling
                const bool renorm = rot && (app > 1e24f);
                if (__any(renorm)) {
                    const float sc = renorm ? rsqrtf(app) : 1.0f;
                    if (renorm) { rho = rho * (app * sc); app = 1.0f; }
                    const f32x4 sc4 = {sc, sc, sc, sc};
#pragma unroll
                    for (int i = 0; i < 16; ++i) fq[i] = fq[i] * sc4;
                }

                if (rot) {  // write updated column back (exec-masked)
                    FOR16(WRF)
                }
            }
            __builtin_amdgcn_wave_barrier();

            quiet = bigr ? 0 : quiet + 1;
            if (quiet >= 63) break;     // all 63 pairings verified quiet
        }
        if (quiet >= 63) break;
    }

    // ---- epilogue: O = U diag(w) U^T ----
    // lambda = rho*sqrt(nrm2_u); U col = fq/sqrt(nrm2_u) (rho cancels).
    float nrm2;
    {
        f32x4 a0 = 0.f, a1 = 0.f, a2 = 0.f, a3 = 0.f;
#pragma unroll
        for (int i = 0; i < 16; i += 4) {
            a0 = __builtin_elementwise_fma(fq[i+0], fq[i+0], a0);
            a1 = __builtin_elementwise_fma(fq[i+1], fq[i+1], a1);
            a2 = __builtin_elementwise_fma(fq[i+2], fq[i+2], a2);
            a3 = __builtin_elementwise_fma(fq[i+3], fq[i+3], a3);
        }
        const f32x4 s = (a0 + a1) + (a2 + a3);
        nrm2 = (s.x + s.y) + (s.z + s.w);
    }
    const float wk  = 0.5f * logf((rho * rho) * nrm2);   // log(lambda)
    const float inv = rsqrtf(nrm2);
    const f32x4 inv4 = {inv, inv, inv, inv};

#define WRU(i, o) { const f32x4 u##i = fq[i] * inv4; DS_WRITE(maddr, u##i, o); }
    FOR16(WRU)                          // row lane = u_lane (normalized)
    T[lane * TSTRIDE + 64] = wk;        // w stored in row padding
    __syncthreads();

    // each lane computes an 8x8 tile of O; O[a][c] = sum_k w_k U[k][a] U[k][c]
    const int la = lane >> 3, lb = lane & 7;
    float acc[8][8];
#pragma unroll
    for (int r0 = 0; r0 < 8; ++r0)
#pragma unroll
        for (int c0 = 0; c0 < 8; ++c0) acc[r0][c0] = 0.f;

#pragma unroll 4
    for (int k = 0; k < 64; ++k) {
        const float wkk = T[k * TSTRIDE + 64];
        const float* row = T + k * TSTRIDE;
        const float4 p0 = *reinterpret_cast<const float4*>(row + la * 8);
        const float4 p1 = *reinterpret_cast<const float4*>(row + la * 8 + 4);
        const float4 u0 = *reinterpret_cast<const float4*>(row + lb * 8);
        const float4 u1 = *reinterpret_cast<const float4*>(row + lb * 8 + 4);
        const float pr[8] = { p0.x*wkk, p0.y*wkk, p0.z*wkk, p0.w*wkk,
                              p1.x*wkk, p1.y*wkk, p1.z*wkk, p1.w*wkk };
        const float uc[8] = { u0.x, u0.y, u0.z, u0.w, u1.x, u1.y, u1.z, u1.w };
#pragma unroll
        for (int r0 = 0; r0 < 8; ++r0)
#pragma unroll
            for (int c0 = 0; c0 < 8; ++c0)
                acc[r0][c0] = fmaf(pr[r0], uc[c0], acc[r0][c0]);
    }

#pragma unroll
    for (int r0 = 0; r0 < 8; ++r0) {
        float* dst = Ob + (la * 8 + r0) * 64 + lb * 8;
        float4 o0 = { acc[r0][0], acc[r0][1], acc[r0][2], acc[r0][3] };
        float4 o1 = { acc[r0][4], acc[r0][5], acc[r0][6], acc[r0][7] };
        reinterpret_cast<float4*>(dst)[0] = o0;
        reinterpret_cast<float4*>(dst)[1] = o1;
    }
}

extern "C" void kernel_launch(void* const* d_in, const int* in_sizes, int n_in,
                              void* d_out, int out_size, void* d_ws, size_t ws_size,
                              hipStream_t stream)
{
    const float* Xp = (const float*)d_in[0];
    float* Op = (float*)d_out;
    const int B = in_sizes[0] / 4096;   // 8192
    logeig_kernel<<<B, 64, 0, stream>>>(Xp, Op, B);
}